// Round 9
// baseline (463.178 us; speedup 1.0000x reference)
//
#include <hip/hip_runtime.h>

// LSTM decoder: B=1024, S=256, H=128, O=7, T=512
// gates = h @ (W_ih+W_hh).T + (b_ih+b_hh); c'=sig(f)c+sig(i)tanh(g);
// h'=sig(o)tanh(c'); pred = h' @ W_out.T + b_out
//
// Round 9 = round 8 structure (32-slot h ring, batched pred every 32 steps,
// zero bank conflicts, no per-step straggler) at RB=2 with 512 blocks ->
// TWO independent blocks per CU (4 waves/SIMD, independent barriers drift
// anti-phase and hide each other's chain latency). This retries rounds
// 2/3/6's occupancy goal with the register set that now fits 128:
// round 8 deleted wpred/pred_lds from the loop (the ~20 regs that caused
// every previous spill). Steady-state live set ~111 regs.

#define HH   128
#define SSEQ 256
#define TT   512
#define OO   7
#define RB   2
#define HSTR 144          // ring row stride in shorts (288B = 8-bank skew)
#define RING 32
#define SLOT (RB * HSTR)  // shorts per ring slot

typedef __attribute__((ext_vector_type(8))) short short8;
typedef __attribute__((ext_vector_type(4))) float f32x4;

__device__ __forceinline__ unsigned short f2bf(float x) {
    union { float f; unsigned u; } v; v.f = x;
    return (unsigned short)((v.u + 0x7FFF + ((v.u >> 16) & 1)) >> 16); // RNE
}
__device__ __forceinline__ float sigmoidf_(float x) {
    return __builtin_amdgcn_rcpf(1.f + __expf(-x));
}
__device__ __forceinline__ float tanhf_(float x) {
    return 1.f - 2.f * __builtin_amdgcn_rcpf(__expf(2.f * x) + 1.f);
}

__global__ void __launch_bounds__(512, 4)
lstm_decoder_kernel(const float* __restrict__ ctx,
                    const float* __restrict__ Wih,
                    const float* __restrict__ Whh,
                    const float* __restrict__ bih,
                    const float* __restrict__ bhh,
                    const float* __restrict__ Wout,
                    const float* __restrict__ bout,
                    float* __restrict__ out) {
    // h ring: slot t&31 holds h_t (bf16), rows padded to HSTR
    __shared__ __align__(16) unsigned short h_ring[RING * SLOT];   // 18 KB
    // W_out B-fragments, lane-indexed (conflict-free): [kt][lane][8]
    __shared__ __align__(16) unsigned short wo_frag[4][64][8];     // 4 KB

    const int tid  = threadIdx.x;
    const int lane = tid & 63;
    const int wave = tid >> 6;
    const int rowBase = blockIdx.x * RB;

    const int lo  = lane & 15;
    const int hi  = lane >> 4;       // 0..3
    const int col = wave * 16 + lo;  // this lane's gate/h column (0..127)
    const int arw = lo & 1;          // A-tile real row (2 rows replicated to 16)
    const int erow = hi & 1;         // elementwise row (dup across hi pairs)

    // folded biases for this lane's column
    const float bi  = bih[col]          + bhh[col];
    const float bf_ = bih[HH + col]     + bhh[HH + col];
    const float bg  = bih[2 * HH + col] + bhh[2 * HH + col];
    const float bo  = bih[3 * HH + col] + bhh[3 * HH + col];
    const float bo_pred = (lo < OO) ? bout[lo] : 0.f;

    // W fragments (B-operand): wave w, gate g -> n = g*128 + w*16 + lo,
    // lane holds W[n][k0..k0+7], k0 = kt*32 + hi*8
    short8 wfrag[4][4];
#pragma unroll
    for (int g = 0; g < 4; ++g) {
        const int n = g * HH + wave * 16 + lo;
#pragma unroll
        for (int kt = 0; kt < 4; ++kt) {
            const int k0 = kt * 32 + hi * 8;
            const float* p1 = Wih + (size_t)n * HH + k0;
            const float* p2 = Whh + (size_t)n * HH + k0;
            short8 w;
#pragma unroll
            for (int j = 0; j < 8; ++j) w[j] = (short)f2bf(p1[j] + p2[j]);
            wfrag[g][kt] = w;
        }
    }

    // W_out B-fragments into LDS (wave 0): lane holds Wout[lo][kt*32+hi*8..+8]
    if (wave == 0) {
#pragma unroll
        for (int kt = 0; kt < 4; ++kt) {
            const int k0 = kt * 32 + hi * 8;
            short8 w;
#pragma unroll
            for (int j = 0; j < 8; ++j)
                w[j] = (lo < OO) ? (short)f2bf(Wout[(size_t)lo * HH + k0 + j]) : (short)0;
            *(short8*)&wo_frag[kt][lane][0] = w;
        }
    }

    // h0 = context_seq[:, S-1, :] -> ring slot 0
    if (hi < RB) {
        const float v = ctx[(size_t)(rowBase + hi) * SSEQ * HH + (size_t)(SSEQ - 1) * HH + col];
        h_ring[hi * HSTR + col] = f2bf(v);
    }
    float c_st = 0.f;   // cell state for (row erow, col); dup across hi pairs
    __syncthreads();

    for (int it = 0; it <= TT; ++it) {
        // ---- batched pred phase: every 32 steps, preds for s = it-32..it-1.
        // Ring: slot 0 holds h_it (s=it-1), slot q>=1 holds h_{it-32+q} (s=it-33+q).
        // 64 pred rows (32 slots x 2 batch rows) = 4 full-M tiles on waves 0..3.
        if (it >= 32 && (it & 31) == 0) {
            if (wave < 4) {
                // A row (within tile) = lo -> global rho = 16*wave + lo
                const int abase = (8 * wave + (lo >> 1)) * SLOT + (lo & 1) * HSTR + hi * 8;
                f32x4 accp = {0.f, 0.f, 0.f, 0.f};
#pragma unroll
                for (int kt = 0; kt < 4; ++kt) {
                    const short8 a  = *(const short8*)&h_ring[abase + kt * 32];
                    const short8 wp = *(const short8*)&wo_frag[kt][lane][0];
                    accp = __builtin_amdgcn_mfma_f32_16x16x32_bf16(a, wp, accp, 0, 0, 0);
                }
                // C: col=lo (output col), row=4*hi+r -> rho=16*wave+4*hi+r
                if (lo < OO) {
#pragma unroll
                    for (int r = 0; r < 4; ++r) {
                        const int q  = 8 * wave + 2 * hi + (r >> 1);
                        const int br = r & 1;
                        const int s  = q ? (it - 33 + q) : (it - 1);
                        out[(size_t)(rowBase + br) * TT * OO + (size_t)s * OO + lo] =
                            accp[r] + bo_pred;
                    }
                }
            }
            __syncthreads();   // pred reads done before slots get overwritten
        }

        if (it == TT) break;

        // ---- LSTM step: h_it (slot it&31) -> h_{it+1} (slot (it+1)&31) ----
        const int abase = (it & 31) * SLOT + arw * HSTR + hi * 8;
        short8 afrag[4];
#pragma unroll
        for (int kt = 0; kt < 4; ++kt)
            afrag[kt] = *(const short8*)&h_ring[abase + kt * 32];

        f32x4 acc0 = {0.f, 0.f, 0.f, 0.f};
        f32x4 acc1 = {0.f, 0.f, 0.f, 0.f};
        f32x4 acc2 = {0.f, 0.f, 0.f, 0.f};
        f32x4 acc3 = {0.f, 0.f, 0.f, 0.f};
#pragma unroll
        for (int kt = 0; kt < 4; ++kt) {
            acc0 = __builtin_amdgcn_mfma_f32_16x16x32_bf16(afrag[kt], wfrag[0][kt], acc0, 0, 0, 0);
            acc1 = __builtin_amdgcn_mfma_f32_16x16x32_bf16(afrag[kt], wfrag[1][kt], acc1, 0, 0, 0);
            acc2 = __builtin_amdgcn_mfma_f32_16x16x32_bf16(afrag[kt], wfrag[2][kt], acc2, 0, 0, 0);
            acc3 = __builtin_amdgcn_mfma_f32_16x16x32_bf16(afrag[kt], wfrag[3][kt], acc3, 0, 0, 0);
        }

        // C row = 4*hi + reg; A row m holds real row m&1 -> reg r at ANY hi is
        // the gate for real row r (r<RB). Select reg r = erow in-register.
        const float gi = erow ? acc0[1] : acc0[0];
        const float gf = erow ? acc1[1] : acc1[0];
        const float gg = erow ? acc2[1] : acc2[0];
        const float go = erow ? acc3[1] : acc3[0];

        const float si_ = sigmoidf_(gi + bi);
        const float sf_ = sigmoidf_(gf + bf_);
        const float so_ = sigmoidf_(go + bo);
        const float tg  = tanhf_(gg + bg);
        c_st = sf_ * c_st + si_ * tg;
        const float hnew = so_ * tanhf_(c_st);

        if (hi < RB)
            h_ring[((it + 1) & 31) * SLOT + hi * HSTR + col] = f2bf(hnew);
        __syncthreads();
    }
}

extern "C" void kernel_launch(void* const* d_in, const int* in_sizes, int n_in,
                              void* d_out, int out_size, void* d_ws, size_t ws_size,
                              hipStream_t stream) {
    const float* ctx  = (const float*)d_in[0];
    const float* Wih  = (const float*)d_in[1];
    const float* Whh  = (const float*)d_in[2];
    const float* bih  = (const float*)d_in[3];
    const float* bhh  = (const float*)d_in[4];
    const float* Wout = (const float*)d_in[5];
    const float* bout = (const float*)d_in[6];
    float* out = (float*)d_out;

    lstm_decoder_kernel<<<dim3(1024 / RB), dim3(512), 0, stream>>>(
        ctx, Wih, Whh, bih, bhh, Wout, bout, out);
}

// Round 10
// 441.450 us; speedup vs baseline: 1.0492x; 1.0492x over previous
//
#include <hip/hip_runtime.h>

// LSTM decoder: B=1024, S=256, H=128, O=7, T=512
// gates = h @ (W_ih+W_hh).T + (b_ih+b_hh); c'=sig(f)c+sig(i)tanh(g);
// h'=sig(o)tanh(c'); pred = h' @ W_out.T + b_out
//
// Round 10: 4-WAVE blocks (256 thr), RB=2, 512 blocks -> 2 independent
// blocks per CU at a 256-reg/wave budget (launch_bounds(256,2)). Each wave
// owns 128 gate-cols: wfrag = 8 tiles = 128 VGPR; total live ~200 <= 256.
// Previous 2-block attempts (rounds 2/3/6/9) all used 8-wave blocks ->
// 128-reg budget -> spill; this is the corner that fits. Round-8 ring +
// batched-pred structure retained (0 bank conflicts, no per-step straggler).
// Biases folded into MFMA C-init; sigmoid/tanh as exp2+rcp chains.

#define HH   128
#define SSEQ 256
#define TT   512
#define OO   7
#define RB   2
#define HSTR 144          // ring row stride in shorts (288B = 8-bank skew)
#define RING 32
#define SLOT (RB * HSTR)  // shorts per ring slot

typedef __attribute__((ext_vector_type(8))) short short8;
typedef __attribute__((ext_vector_type(4))) float f32x4;

__device__ __forceinline__ unsigned short f2bf(float x) {
    union { float f; unsigned u; } v; v.f = x;
    return (unsigned short)((v.u + 0x7FFF + ((v.u >> 16) & 1)) >> 16); // RNE
}
__device__ __forceinline__ float sigm2_(float x) {   // sigmoid, x pre-biased
    return __builtin_amdgcn_rcpf(1.f + __builtin_amdgcn_exp2f(x * -1.44269504f));
}
__device__ __forceinline__ float tanh2_(float x) {
    const float r = __builtin_amdgcn_rcpf(__builtin_amdgcn_exp2f(x * 2.88539008f) + 1.f);
    return __builtin_fmaf(-2.f, r, 1.f);
}

__global__ void __launch_bounds__(256, 2)
lstm_decoder_kernel(const float* __restrict__ ctx,
                    const float* __restrict__ Wih,
                    const float* __restrict__ Whh,
                    const float* __restrict__ bih,
                    const float* __restrict__ bhh,
                    const float* __restrict__ Wout,
                    const float* __restrict__ bout,
                    float* __restrict__ out) {
    // h ring: slot t&31 holds h_t (bf16, RB rows padded to HSTR)
    __shared__ __align__(16) unsigned short h_ring[RING * SLOT];   // 18 KB
    // W_out B-fragments, lane-indexed (conflict-free): [kt][lane][8]
    __shared__ __align__(16) unsigned short wo_frag[4][64][8];     // 4 KB

    const int tid  = threadIdx.x;
    const int lane = tid & 63;
    const int wave = tid >> 6;          // 0..3
    const int rowBase = blockIdx.x * RB;

    const int lo  = lane & 15;
    const int hi  = lane >> 4;          // 0..3
    const int arw = lo & 1;             // A-tile real row (2 rows replicated)
    const int erow = hi >> 1;           // this lane's batch row (0..1)
    const int cbb  = hi & 1;            // this lane's colblock within wave
    const int col  = wave * 32 + cbb * 16 + lo;   // this lane's h column

    // biases for this lane's gate tiles: b4[g][c] = bias of gate g, col 32w+16c+lo
    float b4[4][2];
#pragma unroll
    for (int g = 0; g < 4; ++g)
#pragma unroll
        for (int c = 0; c < 2; ++c) {
            const int j = g * HH + wave * 32 + c * 16 + lo;
            b4[g][c] = bih[j] + bhh[j];
        }
    const float bo_pred = (lo < OO) ? bout[lo] : 0.f;

    // W fragments (B-operand): wave owns colblocks {2w, 2w+1} of each gate.
    // Tile (g,c): n = g*128 + 32w + 16c + lo; lane holds W[n][kt*32+hi*8 ..+8]
    short8 wfrag[4][2][4];   // 128 VGPRs
#pragma unroll
    for (int g = 0; g < 4; ++g)
#pragma unroll
        for (int c = 0; c < 2; ++c) {
            const int n = g * HH + wave * 32 + c * 16 + lo;
#pragma unroll
            for (int kt = 0; kt < 4; ++kt) {
                const int k0 = kt * 32 + hi * 8;
                const float* p1 = Wih + (size_t)n * HH + k0;
                const float* p2 = Whh + (size_t)n * HH + k0;
                short8 w;
#pragma unroll
                for (int j = 0; j < 8; ++j) w[j] = (short)f2bf(p1[j] + p2[j]);
                wfrag[g][c][kt] = w;
            }
        }

    // W_out B-fragments into LDS (wave 0)
    if (wave == 0) {
#pragma unroll
        for (int kt = 0; kt < 4; ++kt) {
            const int k0 = kt * 32 + hi * 8;
            short8 w;
#pragma unroll
            for (int j = 0; j < 8; ++j)
                w[j] = (lo < OO) ? (short)f2bf(Wout[(size_t)lo * HH + k0 + j]) : (short)0;
            *(short8*)&wo_frag[kt][lane][0] = w;
        }
    }

    // h0 = context_seq[:, S-1, :] -> ring slot 0 (each lane owns (erow, col))
    {
        const float v = ctx[(size_t)(rowBase + erow) * SSEQ * HH + (size_t)(SSEQ - 1) * HH + col];
        h_ring[erow * HSTR + col] = f2bf(v);
    }
    float c_st = 0.f;   // cell state for (erow, col)
    __syncthreads();

    for (int it = 0; it <= TT; ++it) {
        // ---- batched pred phase every 32 steps: preds for s = it-32..it-1.
        // Ring: slot 0 = h_it (s=it-1), slot q>=1 = h_{it-32+q} (s=it-33+q).
        // 64 pred rows (32 slots x 2 batch rows) = 4 M-tiles, one per wave.
        if (it >= 32 && (it & 31) == 0) {
            // A row (in tile) = lo -> rho = 16*wave + lo -> slot, batch row
            const int abase = (8 * wave + (lo >> 1)) * SLOT + (lo & 1) * HSTR + hi * 8;
            f32x4 accp = {bo_pred, bo_pred, bo_pred, bo_pred};
#pragma unroll
            for (int kt = 0; kt < 4; ++kt) {
                const short8 a  = *(const short8*)&h_ring[abase + kt * 32];
                const short8 wp = *(const short8*)&wo_frag[kt][lane][0];
                accp = __builtin_amdgcn_mfma_f32_16x16x32_bf16(a, wp, accp, 0, 0, 0);
            }
            if (lo < OO) {
#pragma unroll
                for (int r = 0; r < 4; ++r) {
                    const int q  = 8 * wave + 2 * hi + (r >> 1);  // rho>>1
                    const int br = r & 1;
                    const int s  = q ? (it - 33 + q) : (it - 1);
                    out[(size_t)(rowBase + br) * TT * OO + (size_t)s * OO + lo] = accp[r];
                }
            }
            __syncthreads();   // pred reads done before slots get overwritten
        }

        if (it == TT) break;

        // ---- LSTM step: h_it (slot it&31) -> h_{it+1} ----
        const int abase = (it & 31) * SLOT + arw * HSTR + hi * 8;
        short8 afrag[4];
#pragma unroll
        for (int kt = 0; kt < 4; ++kt)
            afrag[kt] = *(const short8*)&h_ring[abase + kt * 32];

        // 8 tiles (4 gates x 2 colblocks), biases folded into C-init
        f32x4 acc[4][2];
#pragma unroll
        for (int g = 0; g < 4; ++g)
#pragma unroll
            for (int c = 0; c < 2; ++c)
                acc[g][c] = (f32x4){b4[g][c], b4[g][c], b4[g][c], b4[g][c]};
#pragma unroll
        for (int kt = 0; kt < 4; ++kt) {
#pragma unroll
            for (int g = 0; g < 4; ++g)
#pragma unroll
                for (int c = 0; c < 2; ++c)
                    acc[g][c] = __builtin_amdgcn_mfma_f32_16x16x32_bf16(
                        afrag[kt], wfrag[g][c][kt], acc[g][c], 0, 0, 0);
        }

        // C row = 4*hi + r; A row m holds h[m&1] -> reg r holds real row r&1.
        // Lane (erow=hi>>1, cbb=hi&1, col): pick reg r=erow from colblock cbb.
        const float gi = cbb ? (erow ? acc[0][1][1] : acc[0][1][0])
                             : (erow ? acc[0][0][1] : acc[0][0][0]);
        const float gf = cbb ? (erow ? acc[1][1][1] : acc[1][1][0])
                             : (erow ? acc[1][0][1] : acc[1][0][0]);
        const float gg = cbb ? (erow ? acc[2][1][1] : acc[2][1][0])
                             : (erow ? acc[2][0][1] : acc[2][0][0]);
        const float go = cbb ? (erow ? acc[3][1][1] : acc[3][1][0])
                             : (erow ? acc[3][0][1] : acc[3][0][0]);

        const float si_ = sigm2_(gi);
        const float sf_ = sigm2_(gf);
        const float so_ = sigm2_(go);
        const float tg  = tanh2_(gg);
        c_st = __builtin_fmaf(sf_, c_st, si_ * tg);
        const float hnew = so_ * tanh2_(c_st);

        h_ring[((it + 1) & 31) * SLOT + erow * HSTR + col] = f2bf(hnew);
        __syncthreads();
    }
}

extern "C" void kernel_launch(void* const* d_in, const int* in_sizes, int n_in,
                              void* d_out, int out_size, void* d_ws, size_t ws_size,
                              hipStream_t stream) {
    const float* ctx  = (const float*)d_in[0];
    const float* Wih  = (const float*)d_in[1];
    const float* Whh  = (const float*)d_in[2];
    const float* bih  = (const float*)d_in[3];
    const float* bhh  = (const float*)d_in[4];
    const float* Wout = (const float*)d_in[5];
    const float* bout = (const float*)d_in[6];
    float* out = (float*)d_out;

    lstm_decoder_kernel<<<dim3(1024 / RB), dim3(256), 0, stream>>>(
        ctx, Wih, Whh, bih, bhh, Wout, bout, out);
}

// Round 11
// 436.954 us; speedup vs baseline: 1.0600x; 1.0103x over previous
//
#include <hip/hip_runtime.h>

// LSTM decoder: B=1024, S=256, H=128, O=7, T=512
// gates = h @ (W_ih+W_hh).T + (b_ih+b_hh); c'=sig(f)c+sig(i)tanh(g);
// h'=sig(o)tanh(c'); pred = h' @ W_out.T + b_out
//
// Round 11 = round 9 (RB=2, 512 blocks x 512 thr, 32-slot ring, batched
// pred, launch_bounds(512,4) -> 2 blocks/CU) + ~14-reg diet to close the
// ~6-reg spill gap round 9 showed (WRITE 215MB = ~3-6 regs/lane spilled):
//  - biases (5 regs) -> LDS, one ds_read_b128 per step
//  - A-fragments JIT (16 -> 8 live regs): kt-outer with 1-deep prefetch
// Target: no spill at the 128-reg budget; two anti-phase blocks per CU.

#define HH   128
#define SSEQ 256
#define TT   512
#define OO   7
#define RB   2
#define HSTR 144          // ring row stride in shorts (288B = 8-bank skew)
#define RING 32
#define SLOT (RB * HSTR)  // shorts per ring slot

typedef __attribute__((ext_vector_type(8))) short short8;
typedef __attribute__((ext_vector_type(4))) float f32x4;

__device__ __forceinline__ unsigned short f2bf(float x) {
    union { float f; unsigned u; } v; v.f = x;
    return (unsigned short)((v.u + 0x7FFF + ((v.u >> 16) & 1)) >> 16); // RNE
}
__device__ __forceinline__ float sigmoidf_(float x) {
    return __builtin_amdgcn_rcpf(1.f + __expf(-x));
}
__device__ __forceinline__ float tanhf_(float x) {
    return 1.f - 2.f * __builtin_amdgcn_rcpf(__expf(2.f * x) + 1.f);
}

__global__ void __launch_bounds__(512, 4)
lstm_decoder_kernel(const float* __restrict__ ctx,
                    const float* __restrict__ Wih,
                    const float* __restrict__ Whh,
                    const float* __restrict__ bih,
                    const float* __restrict__ bhh,
                    const float* __restrict__ Wout,
                    const float* __restrict__ bout,
                    float* __restrict__ out) {
    // h ring: slot t&31 holds h_t (bf16, RB rows padded to HSTR)
    __shared__ __align__(16) unsigned short h_ring[RING * SLOT];   // 18 KB
    // W_out B-fragments, lane-indexed (conflict-free): [kt][lane][8]
    __shared__ __align__(16) unsigned short wo_frag[4][64][8];     // 4 KB
    // folded gate biases per h-column: [col][i,f,g,o]
    __shared__ __align__(16) float bias_lds[HH][4];                // 2 KB
    __shared__ float bout_lds[16];

    const int tid  = threadIdx.x;
    const int lane = tid & 63;
    const int wave = tid >> 6;
    const int rowBase = blockIdx.x * RB;

    const int lo  = lane & 15;
    const int hi  = lane >> 4;       // 0..3
    const int col = wave * 16 + lo;  // this lane's gate/h column (0..127)
    const int arw = lo & 1;          // A-tile real row (2 rows replicated to 16)
    const int erow = hi & 1;         // elementwise row (dup across hi pairs)

    // W fragments (B-operand): wave w, gate g -> n = g*128 + w*16 + lo,
    // lane holds W[n][k0..k0+7], k0 = kt*32 + hi*8
    short8 wfrag[4][4];
#pragma unroll
    for (int g = 0; g < 4; ++g) {
        const int n = g * HH + wave * 16 + lo;
#pragma unroll
        for (int kt = 0; kt < 4; ++kt) {
            const int k0 = kt * 32 + hi * 8;
            const float* p1 = Wih + (size_t)n * HH + k0;
            const float* p2 = Whh + (size_t)n * HH + k0;
            short8 w;
#pragma unroll
            for (int j = 0; j < 8; ++j) w[j] = (short)f2bf(p1[j] + p2[j]);
            wfrag[g][kt] = w;
        }
    }

    // folded biases -> LDS (threads 0..127, one column each)
    if (tid < HH) {
#pragma unroll
        for (int g = 0; g < 4; ++g)
            bias_lds[tid][g] = bih[g * HH + tid] + bhh[g * HH + tid];
    }
    if (tid < 16) bout_lds[tid] = (tid < OO) ? bout[tid] : 0.f;

    // W_out B-fragments into LDS (wave 1 to spread setup work)
    if (wave == 1) {
#pragma unroll
        for (int kt = 0; kt < 4; ++kt) {
            const int k0 = kt * 32 + hi * 8;
            short8 w;
#pragma unroll
            for (int j = 0; j < 8; ++j)
                w[j] = (lo < OO) ? (short)f2bf(Wout[(size_t)lo * HH + k0 + j]) : (short)0;
            *(short8*)&wo_frag[kt][lane][0] = w;
        }
    }

    // h0 = context_seq[:, S-1, :] -> ring slot 0
    if (hi < RB) {
        const float v = ctx[(size_t)(rowBase + hi) * SSEQ * HH + (size_t)(SSEQ - 1) * HH + col];
        h_ring[hi * HSTR + col] = f2bf(v);
    }
    float c_st = 0.f;   // cell state for (row erow, col); dup across hi pairs
    __syncthreads();

    for (int it = 0; it <= TT; ++it) {
        // ---- batched pred phase every 32 steps: preds for s = it-32..it-1.
        // Ring: slot 0 = h_it (s=it-1), slot q>=1 = h_{it-32+q} (s=it-33+q).
        // 64 pred rows (32 slots x 2 batch rows) = 4 full-M tiles, waves 0..3.
        if (it >= 32 && (it & 31) == 0) {
            if (wave < 4) {
                // A row (within tile) = lo -> rho = 16*wave + lo
                const int abase = (8 * wave + (lo >> 1)) * SLOT + (lo & 1) * HSTR + hi * 8;
                const float bp = bout_lds[lo];
                f32x4 accp = {bp, bp, bp, bp};
#pragma unroll
                for (int kt = 0; kt < 4; ++kt) {
                    const short8 a  = *(const short8*)&h_ring[abase + kt * 32];
                    const short8 wp = *(const short8*)&wo_frag[kt][lane][0];
                    accp = __builtin_amdgcn_mfma_f32_16x16x32_bf16(a, wp, accp, 0, 0, 0);
                }
                // C: col=lo (output col), row=4*hi+r -> rho=16*wave+4*hi+r
                if (lo < OO) {
#pragma unroll
                    for (int r = 0; r < 4; ++r) {
                        const int q  = 8 * wave + 2 * hi + (r >> 1);  // rho>>1
                        const int br = r & 1;
                        const int s  = q ? (it - 33 + q) : (it - 1);
                        out[(size_t)(rowBase + br) * TT * OO + (size_t)s * OO + lo] = accp[r];
                    }
                }
            }
            __syncthreads();   // pred reads done before slots get overwritten
        }

        if (it == TT) break;

        // ---- LSTM step: h_it (slot it&31) -> h_{it+1} ----
        // JIT A-fragments: one short8 live + one prefetch (8 regs, was 16)
        const int abase = (it & 31) * SLOT + arw * HSTR + hi * 8;
        short8 a_cur = *(const short8*)&h_ring[abase];
        f32x4 acc0 = {0.f, 0.f, 0.f, 0.f};
        f32x4 acc1 = {0.f, 0.f, 0.f, 0.f};
        f32x4 acc2 = {0.f, 0.f, 0.f, 0.f};
        f32x4 acc3 = {0.f, 0.f, 0.f, 0.f};
#pragma unroll
        for (int kt = 0; kt < 4; ++kt) {
            short8 a_nxt;
            if (kt < 3) a_nxt = *(const short8*)&h_ring[abase + (kt + 1) * 32];
            acc0 = __builtin_amdgcn_mfma_f32_16x16x32_bf16(a_cur, wfrag[0][kt], acc0, 0, 0, 0);
            acc1 = __builtin_amdgcn_mfma_f32_16x16x32_bf16(a_cur, wfrag[1][kt], acc1, 0, 0, 0);
            acc2 = __builtin_amdgcn_mfma_f32_16x16x32_bf16(a_cur, wfrag[2][kt], acc2, 0, 0, 0);
            acc3 = __builtin_amdgcn_mfma_f32_16x16x32_bf16(a_cur, wfrag[3][kt], acc3, 0, 0, 0);
            if (kt < 3) a_cur = a_nxt;
        }

        // C row = 4*hi + reg; A row m holds real row m&1 -> reg r at ANY hi is
        // the gate for real row r (r<RB). Select reg r = erow in-register.
        const float gi = erow ? acc0[1] : acc0[0];
        const float gf = erow ? acc1[1] : acc1[0];
        const float gg = erow ? acc2[1] : acc2[0];
        const float go = erow ? acc3[1] : acc3[0];

        const f32x4 b4 = *(const f32x4*)&bias_lds[col][0];
        const float si_ = sigmoidf_(gi + b4[0]);
        const float sf_ = sigmoidf_(gf + b4[1]);
        const float tg  = tanhf_(gg + b4[2]);
        const float so_ = sigmoidf_(go + b4[3]);
        c_st = __builtin_fmaf(sf_, c_st, si_ * tg);
        const float hnew = so_ * tanhf_(c_st);

        if (hi < RB)
            h_ring[((it + 1) & 31) * SLOT + hi * HSTR + col] = f2bf(hnew);
        __syncthreads();
    }
}

extern "C" void kernel_launch(void* const* d_in, const int* in_sizes, int n_in,
                              void* d_out, int out_size, void* d_ws, size_t ws_size,
                              hipStream_t stream) {
    const float* ctx  = (const float*)d_in[0];
    const float* Wih  = (const float*)d_in[1];
    const float* Whh  = (const float*)d_in[2];
    const float* bih  = (const float*)d_in[3];
    const float* bhh  = (const float*)d_in[4];
    const float* Wout = (const float*)d_in[5];
    const float* bout = (const float*)d_in[6];
    float* out = (float*)d_out;

    lstm_decoder_kernel<<<dim3(1024 / RB), dim3(512), 0, stream>>>(
        ctx, Wih, Whh, bih, bhh, Wout, bout, out);
}